// Round 11
// baseline (490.266 us; speedup 1.0000x reference)
//
#include <hip/hip_runtime.h>
#include <hip/hip_bf16.h>
#include <stdint.h>

#define NB 4096
#define ND 256
#define NC 32000
#define NCT (NC / 128)   // 250 col-tiles

typedef __bf16 bf16x8 __attribute__((ext_vector_type(8)));
typedef float  f32x4  __attribute__((ext_vector_type(4)));

__device__ __forceinline__ unsigned short f32_to_bf16(float f) {
  union { float f; uint32_t u; } v; v.f = f;
  uint32_t r = v.u + 0x7fffu + ((v.u >> 16) & 1u);
  return (unsigned short)(r >> 16);
}

// DIAGNOSTIC (R11): pure-store stream over d_out, fill-mimic pattern.
// Writes zeros to floats [4, 131072000) of d_out; every byte is later
// overwritten by gemm/finalize, so output is unchanged. Duration of this
// dispatch (inferred from total, or visible in top-5 if slow) measures
// d_out's intrinsic pure-write bandwidth vs fillBufferAligned's 6.9 TB/s
// to d_ws. Healthy -> ~80us. Walled at the 2.2-2.3 TB/s every d_out
// writer has hit -> ~230us.
__global__ void dout_probe_kernel(float* __restrict__ p4) {  // d_out + 4
  const size_t n4 = ((size_t)NB * NC - 4) / 4;   // 32,767,999 f32x4 chunks
  size_t i = (size_t)blockIdx.x * blockDim.x + threadIdx.x;
  const size_t stride = (size_t)gridDim.x * blockDim.x;
  const f32x4 z = {0.f, 0.f, 0.f, 0.f};
  for (; i < n4; i += stride) ((f32x4*)p4)[i] = z;
}

// Cast inputs/V to bf16 in workspace; zero loss accumulator.
__global__ void prep_kernel(const float* __restrict__ inA,
                            const float* __restrict__ inV,
                            unsigned short* __restrict__ outA,
                            unsigned short* __restrict__ outV,
                            float* __restrict__ loss) {
  int gid = blockIdx.x * blockDim.x + threadIdx.x;
  int stride = gridDim.x * blockDim.x;
  if (gid == 0) *loss = 0.f;
  const int nA4 = NB * ND / 4;   // 262144
  const int nV4 = NC * ND / 4;   // 2048000
  for (int i = gid; i < nA4 + nV4; i += stride) {
    float4 v = (i < nA4) ? ((const float4*)inA)[i]
                         : ((const float4*)inV)[i - nA4];
    ushort4 o;
    o.x = f32_to_bf16(v.x);
    o.y = f32_to_bf16(v.y);
    o.z = f32_to_bf16(v.z);
    o.w = f32_to_bf16(v.w);
    if (i < nA4) ((ushort4*)outA)[i] = o;
    else         ((ushort4*)outV)[i - nA4] = o;
  }
}

// R8 kernel unchanged (best base, gemm ~321us): barrier-free K-loop, direct
// global frag loads, swapped-operand MFMA, XCD-swizzled grid, aligned stores
// via -1-column lane rotate, partial-array expsum.
__global__ void __launch_bounds__(256, 2)
gemm_expsum_kernel(const unsigned short* __restrict__ A,
                   const unsigned short* __restrict__ V,
                   float* __restrict__ out,       // d_out + 1 (4B phase!)
                   float* __restrict__ partial) { // [NCT][NB]
  __shared__ float red[2][128];

  const int b = blockIdx.x;
  const int xcd = b & 7;
  const int s = b >> 3;                     // 0..1023 per XCD
  const int colt = (xcd << 5) + (s & 31);   // 32 col-tiles per XCD, col-fast
  const int rowt = s >> 5;                  // 0..31
  if (colt >= NCT) return;                  // padded tail (colt 250..255)
  const int brow = rowt << 7;
  const int bcol = colt << 7;

  const int tid  = threadIdx.x;
  const int lane = tid & 63;
  const int wave = tid >> 6;
  const int wr   = wave >> 1;
  const int wc   = wave & 1;
  const int c16  = lane & 15;
  const int kq   = lane >> 4;      // 0..3

  const __bf16* Ab = (const __bf16*)A;
  const __bf16* Vb = (const __bf16*)V;
  const __bf16* aBase = Ab + (size_t)(brow + wr * 64 + c16) * ND + kq * 8;
  const __bf16* bBase = Vb + (size_t)(bcol + wc * 64 + c16) * ND + kq * 8;

  f32x4 acc[4][4];   // acc[c][r]: c = V-frag (out cols), r = A-frag (out rows)
#pragma unroll
  for (int c = 0; c < 4; ++c)
#pragma unroll
    for (int r = 0; r < 4; ++r)
      acc[c][r] = (f32x4){0.f, 0.f, 0.f, 0.f};

  bf16x8 a0[4], b0[4], a1[4], b1[4];

#define LOADF(AF, BF, KT)                                                     \
  do {                                                                        \
    _Pragma("unroll")                                                         \
    for (int m = 0; m < 4; ++m)                                               \
      AF[m] = *(const bf16x8*)(aBase + (size_t)m * 16 * ND + (KT) * 32);      \
    _Pragma("unroll")                                                         \
    for (int n = 0; n < 4; ++n)                                               \
      BF[n] = *(const bf16x8*)(bBase + (size_t)n * 16 * ND + (KT) * 32);      \
  } while (0)

#define MFMAALL(AF, BF)                                                       \
  do {                                                                        \
    _Pragma("unroll")                                                         \
    for (int c = 0; c < 4; ++c)                                               \
      _Pragma("unroll")                                                       \
      for (int r = 0; r < 4; ++r)                                             \
        acc[c][r] = __builtin_amdgcn_mfma_f32_16x16x32_bf16(BF[c], AF[r],     \
                                                            acc[c][r], 0, 0, 0); \
  } while (0)

  LOADF(a0, b0, 0);
#pragma unroll
  for (int kt = 0; kt < 8; kt += 2) {
    if (kt + 1 < 8) LOADF(a1, b1, kt + 1);
    MFMAALL(a0, b0);
    if (kt + 2 < 8) LOADF(a0, b0, kt + 2);
    MFMAALL(a1, b1);
  }

  // Epilogue: aligned stores via -1-column rotate across lanes (see R8).
  const int colbase = bcol + wc * 64;
  const int srcl = (lane + 16) & 63;
#pragma unroll
  for (int r = 0; r < 4; ++r) {
    const int grow = brow + wr * 64 + r * 16 + c16;
    float* prow0 = out + (size_t)grow * NC + colbase;
    float rsum = 0.f;
#pragma unroll
    for (int c = 0; c < 4; ++c) {
      f32x4 a = acc[c][r];
      rsum += __expf(a[0]) + __expf(a[1]) + __expf(a[2]) + __expf(a[3]);
      const int cs = (c + 1) & 3;
      float g0 = (kq == 0) ? acc[cs][r][0] : a[0];
      float g1 = (kq == 0) ? acc[cs][r][1] : a[1];
      float g2 = (kq == 0) ? acc[cs][r][2] : a[2];
      f32x4 F;
      F[0] = a[3];
      F[1] = __shfl(g0, srcl);
      F[2] = __shfl(g1, srcl);
      F[3] = __shfl(g2, srcl);
      const int t = c * 4 + kq;
      if (t < 15) {
        *(f32x4*)(prow0 + 3 + 4 * t) = F;     // dword idx === 0 (mod 4)
      } else {                                 // chunk {63, 0, 1, 2}
        prow0[63] = F[0];
        prow0[0]  = F[1];
        prow0[1]  = F[2];
        prow0[2]  = F[3];
      }
    }
    rsum += __shfl_xor(rsum, 16);
    rsum += __shfl_xor(rsum, 32);
    if (lane < 16) red[wc][wr * 64 + r * 16 + c16] = rsum;
  }
  __syncthreads();
  if (tid < 128)
    partial[(size_t)colt * NB + brow + tid] = red[0][tid] + red[1][tid];
#undef LOADF
#undef MFMAALL
}

// loss = mean_r( log(sum_c partial[c][r]) - out[r, targets[r]] )
__global__ void finalize_kernel(const float* __restrict__ partial,
                                const float* __restrict__ out,  // d_out + 1
                                const int* __restrict__ targets,
                                float* __restrict__ loss) {
  int r = blockIdx.x * blockDim.x + threadIdx.x;   // 0..NB-1
  float s = 0.f;
  for (int c = 0; c < NCT; ++c) s += partial[(size_t)c * NB + r];
  float li = logf(s) - out[(size_t)r * NC + targets[r]];
#pragma unroll
  for (int o = 32; o > 0; o >>= 1) li += __shfl_down(li, o);
  __shared__ float wsum[4];
  int lane = threadIdx.x & 63, wv = threadIdx.x >> 6;
  if (lane == 0) wsum[wv] = li;
  __syncthreads();
  if (threadIdx.x == 0) {
    float bs = wsum[0] + wsum[1] + wsum[2] + wsum[3];
    atomicAdd(loss, bs * (1.0f / NB));
  }
}

extern "C" void kernel_launch(void* const* d_in, const int* in_sizes, int n_in,
                              void* d_out, int out_size, void* d_ws, size_t ws_size,
                              hipStream_t stream) {
  const float* inputs  = (const float*)d_in[0];
  const int*   targets = (const int*)d_in[1];
  // d_in[2] indexs, d_in[3] label_to_pairs, d_in[4] all_label_to_clusterid: unused (W_MS = 0)
  const float* V       = (const float*)d_in[5];

  float* loss    = (float*)d_out;          // output 0: scalar loss
  float* outputs = (float*)d_out + 1;      // output 1: [4096][32000]

  char* ws = (char*)d_ws;
  unsigned short* Abf = (unsigned short*)ws;                              // 2 MB
  unsigned short* Vbf = (unsigned short*)(ws + (size_t)NB * ND * 2);      // 16.4 MB
  float* partial = (float*)(ws + (size_t)NB * ND * 2 + (size_t)NC * ND * 2); // 3.9 MB

  // DIAGNOSTIC pure-write probe over d_out (overwritten below; see comment).
  hipLaunchKernelGGL(dout_probe_kernel, dim3(2048), dim3(256), 0, stream,
                     (float*)d_out + 4);
  hipLaunchKernelGGL(prep_kernel, dim3(2048), dim3(256), 0, stream,
                     inputs, V, Abf, Vbf, loss);
  // grid: 8 XCDs x 1024 (32 col-tiles x 32 row-tiles), col-tiles padded to 256
  hipLaunchKernelGGL(gemm_expsum_kernel, dim3(8 * 1024), dim3(256), 0, stream,
                     Abf, Vbf, outputs, partial);
  hipLaunchKernelGGL(finalize_kernel, dim3(NB / 256), dim3(256), 0, stream,
                     partial, outputs, targets, loss);
}